// Round 8
// baseline (215.401 us; speedup 1.0000x reference)
//
#include <hip/hip_runtime.h>

#define NHEAD 32
#define LSEQ  2048
#define DIM   64
#define QBLK  64
#define KBLK  64
#define NTILE (LSEQ / KBLK)

typedef float  f32x4  __attribute__((ext_vector_type(4)));
typedef __bf16 bf16x8 __attribute__((ext_vector_type(8)));
typedef unsigned short u16;

__device__ __forceinline__ u16 f2bf(float f) {
    return __builtin_bit_cast(u16, (__bf16)f);   // HW RNE convert
}
__device__ __forceinline__ void st4bf(u16* p, float4 v) {
    union { u16 h[4]; uint2 q; } pk;
    pk.h[0] = f2bf(v.x); pk.h[1] = f2bf(v.y);
    pk.h[2] = f2bf(v.z); pk.h[3] = f2bf(v.w);
    *(uint2*)p = pk.q;
}
__device__ __forceinline__ bf16x8 comb64(const u16* a, const u16* b) {
    union { uint2 q[2]; bf16x8 v; } u;
    u.q[0] = *(const uint2*)a;
    u.q[1] = *(const uint2*)b;
    return u.v;
}

// 0.125 (1/sqrt(64)) * log2(e): softmax computed in exp2 domain
#define QSCALE 0.18033688011112042f
#define RESCALE_THR 8.0f

// ============================================================================
// Pre-pass: K -> bf16 tiles, V -> V^T bf16 tiles (per-lane-fragment layout),
// PLUS the mask^2 loss term. (unchanged from r4/r6/r7, proven)
// ============================================================================
__global__ void prepack_kernel(const float* __restrict__ K,
                               const float* __restrict__ V,
                               const float* __restrict__ Msk,
                               u16* __restrict__ wsK, u16* __restrict__ wsV,
                               float* __restrict__ loss)
{
    __shared__ float sv[64][65];
    __shared__ float red2[4];
    const int b = blockIdx.x;          // head*NTILE + kb
    const int head = b >> 5, kb = b & 31;
    const int t = threadIdx.x;
    const size_t hoff = (size_t)head * LSEQ * DIM;
    const float* Kg = K + hoff + (size_t)(kb * KBLK) * DIM;
    const float* Vg = V + hoff + (size_t)(kb * KBLK) * DIM;
    u16* outK = wsK + (size_t)b * 4096;
    u16* outV = wsV + (size_t)b * 4096;

#pragma unroll
    for (int i = 0; i < 16; ++i) {
        const int e = t + 256 * i;
        sv[e >> 6][e & 63] = Vg[e];
    }
#pragma unroll
    for (int i = 0; i < 2; ++i) {
        const int c = t + 256 * i;
        const int r = c >> 3, q = c & 7;
        const int d0 = 8 * (q ^ (r & 7));
        float4 a  = *(const float4*)(Kg + r * DIM + d0);
        float4 bb = *(const float4*)(Kg + r * DIM + d0 + 4);
        union { u16 h[8]; uint4 u; } pk;
        pk.h[0]=f2bf(a.x);  pk.h[1]=f2bf(a.y);  pk.h[2]=f2bf(a.z);  pk.h[3]=f2bf(a.w);
        pk.h[4]=f2bf(bb.x); pk.h[5]=f2bf(bb.y); pk.h[6]=f2bf(bb.z); pk.h[7]=f2bf(bb.w);
        *(uint4*)(outK + c * 8) = pk.u;
    }
    __syncthreads();
#pragma unroll
    for (int i = 0; i < 2; ++i) {
        const int c = t + 256 * i;
        const int d = c >> 3, q = c & 7;
        const int cl = q ^ (d & 7);
        const int mp = cl >> 2, lq = cl & 3;
        union { u16 h[8]; uint4 u; } pk;
#pragma unroll
        for (int s = 0; s < 2; ++s) {
            const int k0 = 4 * (8 * mp + 4 * s + lq);
#pragma unroll
            for (int j = 0; j < 4; ++j)
                pk.h[4 * s + j] = f2bf(sv[k0 + j][d]);
        }
        *(uint4*)(outV + c * 8) = pk.u;
    }

    float s = 0.f;
    const float4* mq = (const float4*)(Msk + (size_t)b * 4096);
#pragma unroll
    for (int i = 0; i < 4; ++i) {
        float4 v = mq[t + 256 * i];
        s += v.x * v.x + v.y * v.y + v.z * v.z + v.w * v.w;
    }
#pragma unroll
    for (int off = 1; off <= 32; off <<= 1) s += __shfl_xor(s, off);
    if ((t & 63) == 0) red2[t >> 6] = s;
    __syncthreads();
    if (t == 0)
        atomicAdd(loss, 32.0f * (red2[0] + red2[1] + red2[2] + red2[3]));
}

// ============================================================================
// Main fused kernel: BARRIER-FREE / LDS-FREE register streaming.
// Each lane loads its own 16B K/V fragments straight from the prepacked ws
// (same offsets the LDS reads used; data byte-identical). Per-wave pipeline:
//   issue V(p) -> QK(p) [K prefetched] -> softmax(p) [mask prefetched a full
//   period ago] -> issue M(p+1),K(p+1) -> PV(p).
// No __syncthreads, no vmcnt(0) drains: compiler inserts counted vmcnt waits.
// All 4 blocks on a CU stream the same head's K/V -> L1/L2 serves redundancy.
// ============================================================================
__launch_bounds__(256, 3)
__global__ void attn_fused_kernel(const float* __restrict__ Q,
                                  const u16* __restrict__ wsK,
                                  const u16* __restrict__ wsV,
                                  const float* __restrict__ Msk,
                                  float* __restrict__ out,
                                  float* __restrict__ loss)
{
    const int t  = threadIdx.x;
    // bijective XCD-chunked swizzle: 1024 blocks, 8 XCDs, 128-block chunks
    const int wg   = ((int)blockIdx.x & 7) * 128 + ((int)blockIdx.x >> 3);
    const int head = wg >> 5;
    const int qb   = wg & 31;
    const int qbase = qb * QBLK;
    const int w  = t >> 6;
    const int l  = t & 63;
    const int lr = l & 15;
    const int lq = l >> 4;
    const int x7 = lr & 7;

    const size_t hoff = (size_t)head * LSEQ * DIM;
    const int qg = qbase + 16 * w + lr;

    // ---- Q fragments, scale folded in (slots c = 32s + 8lq + j) ----
    bf16x8 qf[2];
#pragma unroll
    for (int s = 0; s < 2; ++s) {
        const float* src = Q + hoff + (size_t)qg * DIM + 32 * s + 8 * lq;
        float4 a = *(const float4*)(src);
        float4 b = *(const float4*)(src + 4);
        union { u16 h[8]; bf16x8 v; } u;
        u.h[0] = f2bf(a.x * QSCALE); u.h[1] = f2bf(a.y * QSCALE);
        u.h[2] = f2bf(a.z * QSCALE); u.h[3] = f2bf(a.w * QSCALE);
        u.h[4] = f2bf(b.x * QSCALE); u.h[5] = f2bf(b.y * QSCALE);
        u.h[6] = f2bf(b.z * QSCALE); u.h[7] = f2bf(b.w * QSCALE);
        qf[s] = u.v;
    }

    f32x4 acc[4];
#pragma unroll
    for (int dt = 0; dt < 4; ++dt) acc[dt] = (f32x4){0.f, 0.f, 0.f, 0.f};
    float mrun = -1e30f, lrun = 0.f, la2 = 0.f, lam = 0.f;

    // lane-constant fragment offsets within a tile image (u16 units);
    // identical to the proven LDS-read addressing of r4-r7
    const int o0 = lr * 64 + ((lq ^ x7) << 3);
    const int o1 = lr * 64 + (((lq + 4) ^ x7) << 3);

    const u16* tK = wsK + (size_t)(head * NTILE) * 4096;
    const u16* tV = wsV + (size_t)(head * NTILE) * 4096;
    const float* mrow = Msk + (size_t)qg * LSEQ + 4 * lq;

    // streaming register state (arrays only ever indexed by unrolled consts)
    bf16x8 kf[8], vf[8];
    f32x4 mM[4];

    // ---- prologue: prefetch K(0), M(0) ----
#pragma unroll
    for (int m = 0; m < 4; ++m) {
        kf[2 * m]     = *(const bf16x8*)(tK + m * 1024 + o0);
        kf[2 * m + 1] = *(const bf16x8*)(tK + m * 1024 + o1);
    }
#pragma unroll
    for (int m = 0; m < 4; ++m) mM[m] = *(const f32x4*)(mrow + 16 * m);

    for (int kb = 0; kb < NTILE; ++kb) {
        // ---- 1. issue V(kb): consumed at PV below (covered by QK+softmax) ----
        const u16* tv = tV + (size_t)kb * 4096;
#pragma unroll
        for (int dt = 0; dt < 4; ++dt) {
            vf[2 * dt]     = *(const bf16x8*)(tv + dt * 1024 + o0);
            vf[2 * dt + 1] = *(const bf16x8*)(tv + dt * 1024 + o1);
        }

        // ---- 2. QK(kb): S^T, D col=q(=lr), row k = 16m + 4lq + r ----
        f32x4 S[4];
        __builtin_amdgcn_s_setprio(1);
#pragma unroll
        for (int m = 0; m < 4; ++m) {
            f32x4 z = (f32x4){0.f, 0.f, 0.f, 0.f};
            z = __builtin_amdgcn_mfma_f32_16x16x32_bf16(kf[2 * m],     qf[0], z, 0, 0, 0);
            z = __builtin_amdgcn_mfma_f32_16x16x32_bf16(kf[2 * m + 1], qf[1], z, 0, 0, 0);
            S[m] = z;
        }
        __builtin_amdgcn_s_setprio(0);

        // ---- 3. softmax-finish (defer-max, shfl-free fast path) ----
        float tm = fmaxf(fmaxf(fmaxf(S[0][0], S[0][1]), fmaxf(S[0][2], S[0][3])),
                         fmaxf(fmaxf(S[1][0], S[1][1]), fmaxf(S[1][2], S[1][3])));
        tm = fmaxf(tm, fmaxf(fmaxf(fmaxf(S[2][0], S[2][1]), fmaxf(S[2][2], S[2][3])),
                             fmaxf(fmaxf(S[3][0], S[3][1]), fmaxf(S[3][2], S[3][3]))));
        if (!__all(tm - mrun <= RESCALE_THR)) {      // wave-uniform branch
            tm = fmaxf(tm, __shfl_xor(tm, 16));      // cross-lane only when rescaling
            tm = fmaxf(tm, __shfl_xor(tm, 32));
            const float mn = fmaxf(mrun, tm);
            const float al = __builtin_amdgcn_exp2f(mrun - mn);
            mrun = mn;
            lrun *= al; la2 *= al * al; lam *= al;
#pragma unroll
            for (int dt = 0; dt < 4; ++dt) acc[dt] *= al;
        }

        float psum = 0.f, pp2 = 0.f, ppm = 0.f;
        u16 pb[16];
#pragma unroll
        for (int m = 0; m < 4; ++m) {
#pragma unroll
            for (int r = 0; r < 4; ++r) {
                float p = __builtin_amdgcn_exp2f(S[m][r] - mrun);
                psum += p;
                pp2  += p * p;
                ppm  += p * mM[m][r];
                pb[4 * m + r] = f2bf(p);
            }
        }
        lrun += psum; la2 += pp2; lam += ppm;

        // ---- 4. issue M(kb+1) then K(kb+1): full-period prefetch distance;
        //      M older than K in vmcnt order, so QK's counted wait covers both ----
        if (kb + 1 < NTILE) {
            const float* mr2 = mrow + (size_t)(kb + 1) * KBLK;
#pragma unroll
            for (int m = 0; m < 4; ++m) mM[m] = *(const f32x4*)(mr2 + 16 * m);
            const u16* tk2 = tK + (size_t)(kb + 1) * 4096;
#pragma unroll
            for (int m = 0; m < 4; ++m) {
                kf[2 * m]     = *(const bf16x8*)(tk2 + m * 1024 + o0);
                kf[2 * m + 1] = *(const bf16x8*)(tk2 + m * 1024 + o1);
            }
        }

        // ---- 5. PV(kb): O^T += V^T * P ----
        bf16x8 pf0, pf1;
        {
            union { u16 h[8]; bf16x8 v; } u;
            u.h[0] = pb[0]; u.h[1] = pb[1]; u.h[2] = pb[2]; u.h[3] = pb[3];
            u.h[4] = pb[4]; u.h[5] = pb[5]; u.h[6] = pb[6]; u.h[7] = pb[7];
            pf0 = u.v;
        }
        {
            union { u16 h[8]; bf16x8 v; } u;
            u.h[0] = pb[8];  u.h[1] = pb[9];  u.h[2] = pb[10]; u.h[3] = pb[11];
            u.h[4] = pb[12]; u.h[5] = pb[13]; u.h[6] = pb[14]; u.h[7] = pb[15];
            pf1 = u.v;
        }
        __builtin_amdgcn_s_setprio(1);
#pragma unroll
        for (int dt = 0; dt < 4; ++dt) {
            acc[dt] = __builtin_amdgcn_mfma_f32_16x16x32_bf16(vf[2 * dt],     pf0, acc[dt], 0, 0, 0);
            acc[dt] = __builtin_amdgcn_mfma_f32_16x16x32_bf16(vf[2 * dt + 1], pf1, acc[dt], 0, 0, 0);
        }
        __builtin_amdgcn_s_setprio(0);
    }

    // ---- reduce per-lane partials across the 4 k-groups ----
#pragma unroll
    for (int off = 16; off <= 32; off <<= 1) {
        lrun += __shfl_xor(lrun, off);
        la2  += __shfl_xor(la2,  off);
        lam  += __shfl_xor(lam,  off);
    }

    const float inv = 1.0f / lrun;

#pragma unroll
    for (int dt = 0; dt < 4; ++dt) {
        float4 o;
        o.x = acc[dt][0] * inv; o.y = acc[dt][1] * inv;
        o.z = acc[dt][2] * inv; o.w = acc[dt][3] * inv;
        *(float4*)(out + hoff + (size_t)qg * DIM + 16 * dt + 4 * lq) = o;
    }

    float part = la2 * inv * inv - 2.0f * lam * inv;
    part = (l < 16) ? part : 0.f;
#pragma unroll
    for (int off = 1; off <= 8; off <<= 1) part += __shfl_xor(part, off);
    if (l == 0) atomicAdd(loss, part);
}

// ============================================================================
// Fallback (proven r3 kernel) + standalone masksq if workspace too small.
// ============================================================================
__global__ void masksq_kernel(const float* __restrict__ Msk, float* __restrict__ loss)
{
    __shared__ float red[4];
    float s = 0.f;
    const size_t n4 = (size_t)LSEQ * LSEQ / 4;
    for (size_t i = (size_t)blockIdx.x * blockDim.x + threadIdx.x; i < n4;
         i += (size_t)gridDim.x * blockDim.x) {
        float4 v = ((const float4*)Msk)[i];
        s += v.x * v.x + v.y * v.y + v.z * v.z + v.w * v.w;
    }
#pragma unroll
    for (int off = 1; off <= 32; off <<= 1) s += __shfl_xor(s, off);
    if ((threadIdx.x & 63) == 0) red[threadIdx.x >> 6] = s;
    __syncthreads();
    if (threadIdx.x == 0) {
        float tot = red[0] + red[1] + red[2] + red[3];
        atomicAdd(loss, 32.0f * tot);
    }
}

__launch_bounds__(256, 4)
__global__ void attn_fallback_kernel(const float* __restrict__ Q,
                                     const float* __restrict__ K,
                                     const float* __restrict__ V,
                                     const float* __restrict__ Msk,
                                     float* __restrict__ out,
                                     float* __restrict__ loss)
{
    __shared__ __align__(16) u16 lds_k[64][72];
    __shared__ __align__(16) u16 lds_v[64][68];

    const int t  = threadIdx.x;
    const int wg   = ((int)blockIdx.x & 7) * 128 + ((int)blockIdx.x >> 3);
    const int head = wg >> 5;
    const int qb   = wg & 31;
    const int qbase = qb * QBLK;
    const int w  = t >> 6;
    const int l  = t & 63;
    const int lr = l & 15;
    const int lq = l >> 4;

    const size_t hoff = (size_t)head * LSEQ * DIM;
    const int qg = qbase + 16 * w + lr;

    bf16x8 qf[2];
#pragma unroll
    for (int s = 0; s < 2; ++s) {
        const float* src = Q + hoff + (size_t)qg * DIM + 32 * s + 8 * lq;
        float4 a = *(const float4*)(src);
        float4 b = *(const float4*)(src + 4);
        union { u16 h[8]; bf16x8 v; } u;
        u.h[0] = f2bf(a.x * QSCALE); u.h[1] = f2bf(a.y * QSCALE);
        u.h[2] = f2bf(a.z * QSCALE); u.h[3] = f2bf(a.w * QSCALE);
        u.h[4] = f2bf(b.x * QSCALE); u.h[5] = f2bf(b.y * QSCALE);
        u.h[6] = f2bf(b.z * QSCALE); u.h[7] = f2bf(b.w * QSCALE);
        qf[s] = u.v;
    }

    f32x4 acc[4];
#pragma unroll
    for (int dt = 0; dt < 4; ++dt) acc[dt] = (f32x4){0.f, 0.f, 0.f, 0.f};
    float mrun = -1e30f, lrun = 0.f, la2 = 0.f, lam = 0.f;

    for (int kb = 0; kb < NTILE; ++kb) {
        const int kbase = kb * KBLK;
        __syncthreads();
        f32x4 mreg[4];
        {
            const float* mp_ = Msk + (size_t)qg * LSEQ + kbase + 4 * lq;
#pragma unroll
            for (int m = 0; m < 4; ++m)
                mreg[m] = *(const f32x4*)(mp_ + 16 * m);
        }
        {
            const float* Kg = K + hoff + (size_t)kbase * DIM;
            const float* Vg = V + hoff + (size_t)kbase * DIM;
#pragma unroll
            for (int i = 0; i < 4; ++i) {
                const int id = t + 256 * i;
                const int r = id >> 4, c = (id & 15) * 4;
                float4 kv = *(const float4*)(Kg + r * DIM + c);
                float4 vv = *(const float4*)(Vg + r * DIM + c);
                st4bf(&lds_k[r][c], kv);
                lds_v[c + 0][r] = f2bf(vv.x);
                lds_v[c + 1][r] = f2bf(vv.y);
                lds_v[c + 2][r] = f2bf(vv.z);
                lds_v[c + 3][r] = f2bf(vv.w);
            }
        }
        __syncthreads();

        f32x4 S[4];
#pragma unroll
        for (int m = 0; m < 4; ++m) {
            bf16x8 kf0 = *(const bf16x8*)&lds_k[16 * m + lr][8 * lq];
            bf16x8 kf1 = *(const bf16x8*)&lds_k[16 * m + lr][32 + 8 * lq];
            f32x4 z = (f32x4){0.f, 0.f, 0.f, 0.f};
            z = __builtin_amdgcn_mfma_f32_16x16x32_bf16(kf0, qf[0], z, 0, 0, 0);
            z = __builtin_amdgcn_mfma_f32_16x16x32_bf16(kf1, qf[1], z, 0, 0, 0);
            S[m] = z;
        }

        float tm = fmaxf(fmaxf(fmaxf(S[0][0], S[0][1]), fmaxf(S[0][2], S[0][3])),
                         fmaxf(fmaxf(S[1][0], S[1][1]), fmaxf(S[1][2], S[1][3])));
        tm = fmaxf(tm, fmaxf(fmaxf(fmaxf(S[2][0], S[2][1]), fmaxf(S[2][2], S[2][3])),
                             fmaxf(fmaxf(S[3][0], S[3][1]), fmaxf(S[3][2], S[3][3]))));
        tm = fmaxf(tm, __shfl_xor(tm, 16));
        tm = fmaxf(tm, __shfl_xor(tm, 32));
        if (!__all(tm - mrun <= RESCALE_THR)) {
            const float mn = fmaxf(mrun, tm);
            const float al = __builtin_amdgcn_exp2f(mrun - mn);
            mrun = mn;
            lrun *= al; la2 *= al * al; lam *= al;
#pragma unroll
            for (int dt = 0; dt < 4; ++dt) acc[dt] *= al;
        }

        float psum = 0.f, pp2 = 0.f, ppm = 0.f;
        u16 pb[16];
#pragma unroll
        for (int m = 0; m < 4; ++m) {
#pragma unroll
            for (int r = 0; r < 4; ++r) {
                float p = __builtin_amdgcn_exp2f(S[m][r] - mrun);
                psum += p;
                pp2  += p * p;
                ppm  += p * mreg[m][r];
                pb[4 * m + r] = f2bf(p);
            }
        }
        lrun += psum; la2 += pp2; lam += ppm;

        bf16x8 pf[2];
#pragma unroll
        for (int mp = 0; mp < 2; ++mp) {
            union { u16 h[8]; bf16x8 v; } u;
#pragma unroll
            for (int j = 0; j < 4; ++j) { u.h[j] = pb[8 * mp + j]; u.h[4 + j] = pb[8 * mp + 4 + j]; }
            pf[mp] = u.v;
        }
#pragma unroll
        for (int dt = 0; dt < 4; ++dt) {
#pragma unroll
            for (int mp = 0; mp < 2; ++mp) {
                bf16x8 vf = comb64(&lds_v[16 * dt + lr][32 * mp + 4 * lq],
                                   &lds_v[16 * dt + lr][32 * mp + 16 + 4 * lq]);
                acc[dt] = __builtin_amdgcn_mfma_f32_16x16x32_bf16(vf, pf[mp], acc[dt], 0, 0, 0);
            }
        }
    }

#pragma unroll
    for (int off = 16; off <= 32; off <<= 1) {
        lrun += __shfl_xor(lrun, off);
        la2  += __shfl_xor(la2,  off);
        lam  += __shfl_xor(lam,  off);
    }
    const float inv = 1.0f / lrun;
#pragma unroll
    for (int dt = 0; dt < 4; ++dt) {
        float4 o;
        o.x = acc[dt][0] * inv; o.y = acc[dt][1] * inv;
        o.z = acc[dt][2] * inv; o.w = acc[dt][3] * inv;
        *(float4*)(out + hoff + (size_t)qg * DIM + 16 * dt + 4 * lq) = o;
    }
    float part = la2 * inv * inv - 2.0f * lam * inv;
    part = (l < 16) ? part : 0.f;
#pragma unroll
    for (int off = 1; off <= 8; off <<= 1) part += __shfl_xor(part, off);
    if (l == 0) atomicAdd(loss, part);
}

extern "C" void kernel_launch(void* const* d_in, const int* in_sizes, int n_in,
                              void* d_out, int out_size, void* d_ws, size_t ws_size,
                              hipStream_t stream)
{
    const float* Q   = (const float*)d_in[0];
    const float* K   = (const float*)d_in[1];
    const float* V   = (const float*)d_in[2];
    const float* Msk = (const float*)d_in[3];
    float* out  = (float*)d_out;
    float* loss = out + (size_t)NHEAD * LSEQ * DIM;  // element 4194304

    hipMemsetAsync(loss, 0, sizeof(float), stream);

    const size_t need = (size_t)2 * NHEAD * NTILE * 4096 * sizeof(u16);  // 16 MB
    if (d_ws && ws_size >= need) {
        u16* wsK = (u16*)d_ws;
        u16* wsV = wsK + (size_t)NHEAD * NTILE * 4096;
        prepack_kernel<<<NHEAD * NTILE, 256, 0, stream>>>(K, V, Msk, wsK, wsV, loss);
        attn_fused_kernel<<<NHEAD * (LSEQ / QBLK), 256, 0, stream>>>(Q, wsK, wsV, Msk, out, loss);
    } else {
        masksq_kernel<<<256, 256, 0, stream>>>(Msk, loss);
        attn_fallback_kernel<<<NHEAD * (LSEQ / QBLK), 256, 0, stream>>>(Q, K, V, Msk, out, loss);
    }
}